// Round 1
// baseline (205.761 us; speedup 1.0000x reference)
//
#include <hip/hip_runtime.h>
#include <stdint.h>

#define BATCH 4
#define N1D   2048
#define N2D   8192
#define NSAMP 32
#define NKP   15
#define CIN   64
#define COUT  128

#define RAD2    0.01f     // RADIUS^2
#define INV_EXT 25.0f     // 1 / EXTENT (EXTENT = 0.04)
#define BN_EPS  1e-5f

#define QPW   4                 // queries per wave
#define NWAVE 4                 // waves per block (block = 256)
#define QPB   (QPW*NWAVE)       // 16 queries per block
#define CHUNK 256               // staged support points per chunk
#define NCHUNK (N2D/CHUNK)      // 32

// ---- ws layout (in floats) ----
#define WS_PTS4   0                        // float4[B*N2]            131072 floats
#define WS_FEATT  131072                   // float [B*N2*CIN]       2097152 floats
#define WS_X1     (131072+2097152)         // float [B*N1*CIN]        524288 floats
#define WS_OUT2   (2228224+524288)         // float [B*COUT*N1]      1048576 floats
#define WS_STATS  (2752512+1048576)        // float [2*COUT] sums

// ---------------------------------------------------------------------------
// prep: pack support points (mask folded into coords), transpose features to
// [B][N2][C], zero the BN stat accumulators.
// grid = 257 blocks x 256
// ---------------------------------------------------------------------------
__global__ __launch_bounds__(256) void pg_prep(
    const float* __restrict__ sxyz, const float* __restrict__ smask,
    const float* __restrict__ sfeat, float4* __restrict__ pts4,
    float* __restrict__ featT, float* __restrict__ stats)
{
  const int blk = blockIdx.x;
  const int t = threadIdx.x;
  if (blk < 128) {
    // pack points: g in [0, B*N2)
    const int g = blk*256 + t;
    const float m = smask[g];
    float x = sxyz[g*3+0], y = sxyz[g*3+1], z = sxyz[g*3+2];
    if (m <= 0.0f) { x = 1e30f; y = 1e30f; z = 1e30f; }   // masked -> never valid
    pts4[g] = make_float4(x, y, z, 0.0f);
  } else if (blk < 256) {
    // transpose features: block handles 256 consecutive j for one batch
    const int fb = blk - 128;
    const int b  = fb >> 5;              // 32 blocks per batch
    const int j  = ((fb & 31) << 8) + t;
    const float* src = sfeat + (b*CIN)*N2D + j;          // stride N2D per channel
    float4* dst = (float4*)(featT + (b*N2D + j)*CIN);
#pragma unroll
    for (int c0 = 0; c0 < CIN; c0 += 4) {
      float4 v;
      v.x = src[(c0+0)*N2D];
      v.y = src[(c0+1)*N2D];
      v.z = src[(c0+2)*N2D];
      v.w = src[(c0+3)*N2D];
      dst[c0 >> 2] = v;
    }
  } else {
    stats[t] = 0.0f;   // 256 floats: sum[128], sumsq[128]
  }
}

// ---------------------------------------------------------------------------
// main: ordered ball query + kernel-point weights + weighted feature sum.
// grid = 512 blocks x 256 (16 queries per block, 4 per wave)
// ---------------------------------------------------------------------------
__global__ __launch_bounds__(256) void pg_main(
    const float* __restrict__ qxyz, const float* __restrict__ sxyz,
    const float* __restrict__ qmask, const float4* __restrict__ pts4,
    const float* __restrict__ featT, const float* __restrict__ Kp,
    const float* __restrict__ KW, float* __restrict__ x1)
{
  __shared__ float4   s_pts[2][CHUNK];       // 8 KB, double-buffered staging
  __shared__ int      s_idx[QPB*NSAMP];      // 2 KB
  __shared__ int      s_cnt[QPB];
  __shared__ float    s_w[QPB*NSAMP*17];     // 34.8 KB (pad 17 breaks conflicts)
  __shared__ unsigned s_wm[QPB*NSAMP];       // 2 KB active-k bitmasks

  const int t    = threadIdx.x;
  const int lane = t & 63;
  const int wv   = t >> 6;
  const int gbase = blockIdx.x * QPB;        // 2048 % 16 == 0 -> single batch
  const int b     = gbase >> 11;

  // ---- phase 1: ordered ball query ----
  float qx[QPW], qy[QPW], qz[QPW];
  int cnt[QPW];
#pragma unroll
  for (int q = 0; q < QPW; ++q) {
    const int g = gbase + wv*QPW + q;
    qx[q] = qxyz[g*3+0]; qy[q] = qxyz[g*3+1]; qz[q] = qxyz[g*3+2];
    cnt[q] = 0;
  }

  const float4* bp = pts4 + b*N2D;
  float4 v = bp[t];                          // prefetch chunk 0
  bool wdone = false;
  const uint64_t lt = (1ull << lane) - 1ull;

  for (int ch = 0; ch < NCHUNK; ++ch) {
    const int buf = ch & 1;
    s_pts[buf][t] = v;
    if (ch + 1 < NCHUNK) v = bp[(ch+1)*CHUNK + t];   // prefetch next chunk
    __syncthreads();
    if (!wdone) {
#pragma unroll
      for (int sub = 0; sub < CHUNK/64; ++sub) {
        const float4 p = s_pts[buf][sub*64 + lane];
        const int jj = ch*CHUNK + sub*64 + lane;
#pragma unroll
        for (int q = 0; q < QPW; ++q) {
          const float dx = p.x - qx[q];
          const float dy = p.y - qy[q];
          const float dz = p.z - qz[q];
          const float d2 = dx*dx + dy*dy + dz*dz;
          const bool valid = d2 < RAD2;               // mask folded into coords
          const uint64_t m = __ballot(valid);
          if (valid) {
            const int pos = cnt[q] + __popcll(m & lt);
            if (pos < NSAMP) s_idx[(wv*QPW + q)*NSAMP + pos] = jj;
          }
          cnt[q] += (int)__popcll(m);
        }
      }
      if (cnt[0] >= NSAMP && cnt[1] >= NSAMP && cnt[2] >= NSAMP && cnt[3] >= NSAMP)
        wdone = true;                                  // wave-uniform skip
    }
  }

  if (lane == 0) {
#pragma unroll
    for (int q = 0; q < QPW; ++q) {
      int c = cnt[q]; if (c > NSAMP) c = NSAMP;
      s_cnt[wv*QPW + q] = c;
    }
  }
  __syncthreads();

  // ---- phase 2a: pad-normalize idx, rel vectors, per-(q,s,k) weights ----
  // thread t owns slots qs=t and qs=t+256 -> register-private rel & bitmask
  float rx[2], ry[2], rz[2];
#pragma unroll
  for (int h = 0; h < 2; ++h) {
    const int qs = t + h*256;
    const int q = qs >> 5;
    const int s = qs & 31;
    const int c = s_cnt[q];
    int j;
    if (s < c) {
      j = s_idx[qs];
    } else {
      j = (c > 0) ? s_idx[q*NSAMP] : 0;   // pad with first neighbor (ref semantics)
      s_idx[qs] = j;
    }
    const int g = gbase + q;
    rx[h] = sxyz[(b*N2D + j)*3 + 0] - qxyz[g*3+0];
    ry[h] = sxyz[(b*N2D + j)*3 + 1] - qxyz[g*3+1];
    rz[h] = sxyz[(b*N2D + j)*3 + 2] - qxyz[g*3+2];
  }

  unsigned msk0 = 0u, msk1 = 0u;
#pragma unroll
  for (int i = 0; i < 2*NKP; ++i) {
    const int k = i >> 1;                 // uniform per iteration -> Kp scalar loads
    const int h = i & 1;
    const float dx = (h ? rx[1] : rx[0]) - Kp[k*3+0];
    const float dy = (h ? ry[1] : ry[0]) - Kp[k*3+1];
    const float dz = (h ? rz[1] : rz[0]) - Kp[k*3+2];
    const float dd = dx*dx + dy*dy + dz*dz;
    const float w = 1.0f - sqrtf(dd) * INV_EXT;
    if (w > 0.0f) {
      s_w[(t + h*256)*17 + k] = w;
      if (h) msk1 |= (1u << k); else msk0 |= (1u << k);
    }
  }
  s_wm[t]       = msk0;
  s_wm[t + 256] = msk1;
  __syncthreads();

  // ---- phase 2b: weighted feature aggregation (lane = channel) ----
  float kw[NKP];
#pragma unroll
  for (int k = 0; k < NKP; ++k) kw[k] = KW[k*CIN + lane];

#pragma unroll
  for (int qi = 0; qi < QPW; ++qi) {
    const int ql = wv*QPW + qi;
    const int g = gbase + ql;
    const float qm = qmask[g];
    const float fpad = 1.0f - qm;          // feature_mask = nb_mask + (1 - qmask)
    const int c = s_cnt[ql];
    float acc = 0.0f;
    for (int s = 0; s < NSAMP; ++s) {
      const float fm = (s < c) ? (1.0f + fpad) : fpad;
      if (fm != 0.0f) {
        const unsigned mk =
            (unsigned)__builtin_amdgcn_readfirstlane((int)s_wm[ql*NSAMP + s]);
        if (mk != 0u) {
          const int j = s_idx[ql*NSAMP + s];
          const float ft = featT[(b*N2D + j)*CIN + lane];
          const float* wp = &s_w[(ql*NSAMP + s)*17];
          float wsum = 0.0f;
#pragma unroll
          for (int k = 0; k < NKP; ++k)
            if (mk & (1u << k)) wsum += wp[k] * kw[k];   // kw[k] literal index
          acc += fm * wsum * ft;
        }
      }
    }
    x1[g*CIN + lane] = acc;
  }
}

// ---------------------------------------------------------------------------
// conv: out2[b,o,n] = sum_c W[o,c] * x1[g,c], fused BN sum/sumsq atomics.
// grid = 256 blocks x 256 (block = 64 queries x 64 output channels)
// ---------------------------------------------------------------------------
__global__ __launch_bounds__(256) void pg_conv(
    const float* __restrict__ x1, const float* __restrict__ Wout,
    float* __restrict__ out2, float* __restrict__ stats)
{
  __shared__ float s_x[64*65];
  const int t = threadIdx.x;
  const int lane = t & 63;
  const int wv = t >> 6;
  const int gt = blockIdx.x >> 1;
  const int oh = blockIdx.x & 1;
  const int g0 = gt * 64;
#pragma unroll
  for (int i = 0; i < 16; ++i) {
    const int idx = i*256 + t;
    s_x[(idx >> 6)*65 + (idx & 63)] = x1[g0*64 + idx];   // coalesced, +1 pad
  }
  __syncthreads();
  float xv[64];
#pragma unroll
  for (int cc = 0; cc < 64; ++cc) xv[cc] = s_x[lane*65 + cc];
  const int g = g0 + lane;
  const int bb = g >> 11;
  const int nn = g & 2047;
#pragma unroll
  for (int oi = 0; oi < 16; ++oi) {
    const int o = oh*64 + wv*16 + oi;
    const float* wr = Wout + o*CIN;                       // uniform -> s_load
    float acc = 0.0f;
#pragma unroll
    for (int cc = 0; cc < 64; ++cc) acc = fmaf(wr[cc], xv[cc], acc);
    out2[(bb*COUT + o)*N1D + nn] = acc;
    float s1 = acc, s2 = acc*acc;
#pragma unroll
    for (int off = 32; off; off >>= 1) {
      s1 += __shfl_xor(s1, off);
      s2 += __shfl_xor(s2, off);
    }
    if (lane == 0) {
      atomicAdd(&stats[o], s1);
      atomicAdd(&stats[COUT + o], s2);
    }
  }
}

// ---------------------------------------------------------------------------
// apply: BN (batch stats) + gamma/beta + ReLU.  grid = 1024 x 256, float4.
// ---------------------------------------------------------------------------
__global__ __launch_bounds__(256) void pg_apply(
    const float* __restrict__ out2, const float* __restrict__ stats,
    const float* __restrict__ gamma, const float* __restrict__ beta,
    float* __restrict__ dout)
{
  const int i = blockIdx.x*256 + threadIdx.x;   // float4 index
  const int flat = i*4;
  const int o = (flat >> 11) & 127;             // uniform per block
  const float inv = 1.0f / (float)(BATCH*N1D);
  const float mean = stats[o] * inv;
  const float var = stats[COUT + o] * inv - mean*mean;
  const float istd = rsqrtf(var + BN_EPS);
  const float ga = gamma[o] * istd;
  const float be = beta[o];
  const float4 x = ((const float4*)out2)[i];
  float4 y;
  y.x = fmaxf((x.x - mean)*ga + be, 0.0f);
  y.y = fmaxf((x.y - mean)*ga + be, 0.0f);
  y.z = fmaxf((x.z - mean)*ga + be, 0.0f);
  y.w = fmaxf((x.w - mean)*ga + be, 0.0f);
  ((float4*)dout)[i] = y;
}

extern "C" void kernel_launch(void* const* d_in, const int* in_sizes, int n_in,
                              void* d_out, int out_size, void* d_ws, size_t ws_size,
                              hipStream_t stream)
{
  const float* qxyz  = (const float*)d_in[0];
  const float* sxyz  = (const float*)d_in[1];
  const float* qmask = (const float*)d_in[2];
  const float* smask = (const float*)d_in[3];
  const float* sfeat = (const float*)d_in[4];
  const float* Kp    = (const float*)d_in[5];
  const float* KW    = (const float*)d_in[6];
  const float* Wout  = (const float*)d_in[7];
  const float* gamma = (const float*)d_in[8];
  const float* beta  = (const float*)d_in[9];
  float* ws = (float*)d_ws;
  float4* pts4 = (float4*)(ws + WS_PTS4);
  float* featT = ws + WS_FEATT;
  float* x1    = ws + WS_X1;
  float* out2  = ws + WS_OUT2;
  float* stats = ws + WS_STATS;
  float* dst   = (float*)d_out;

  pg_prep <<<257,  256, 0, stream>>>(sxyz, smask, sfeat, pts4, featT, stats);
  pg_main <<<512,  256, 0, stream>>>(qxyz, sxyz, qmask, pts4, featT, Kp, KW, x1);
  pg_conv <<<256,  256, 0, stream>>>(x1, Wout, out2, stats);
  pg_apply<<<1024, 256, 0, stream>>>(out2, stats, gamma, beta, dst);
}

// Round 2
// 177.782 us; speedup vs baseline: 1.1574x; 1.1574x over previous
//
#include <hip/hip_runtime.h>
#include <stdint.h>

#define BATCH 4
#define N1D   2048
#define N2D   8192
#define NSAMP 32
#define NKP   15
#define CIN   64
#define COUT  128

#define RAD2    0.01f     // RADIUS^2
#define INV_EXT 25.0f     // 1 / EXTENT (EXTENT = 0.04)
#define BN_EPS  1e-5f

#define QPW   2                 // queries per wave
#define NWAVE 4                 // waves per block (block = 256)
#define QPB   (QPW*NWAVE)       // 8 queries per block
#define CHUNK 256               // staged support points per chunk
#define NCHUNK (N2D/CHUNK)      // 32

// ---- ws layout (in floats) ----
#define WS_PTS4   0                        // float4[B*N2]            131072 floats
#define WS_FEATT  131072                   // float [B*N2*CIN]       2097152 floats
#define WS_X1     (131072+2097152)         // float [B*N1*CIN]        524288 floats
#define WS_OUT2   (2228224+524288)         // float [B*COUT*N1]      1048576 floats
#define WS_STATS  (2752512+1048576)        // float [2*COUT] sums

// ---------------------------------------------------------------------------
// prep: LDS-tiled feature transpose (coalesced read AND write), point packing
// (mask folded into coords), BN stat zeroing.  grid = 512 x 256.
// Block bt: batch b = bt>>7, j-tile j0 = (bt&127)*64.
// ---------------------------------------------------------------------------
__global__ __launch_bounds__(256) void pg_prep(
    const float* __restrict__ sxyz, const float* __restrict__ smask,
    const float* __restrict__ sfeat, float4* __restrict__ pts4,
    float* __restrict__ featT, float* __restrict__ stats)
{
  __shared__ float tile[64*65];
  const int t  = threadIdx.x;
  const int bt = blockIdx.x;
  const int b  = bt >> 7;
  const int j0 = (bt & 127) * 64;

  // pack 64 support points per block (first wave)
  if (t < 64) {
    const int g = bt*64 + t;          // 512*64 = 32768 = B*N2
    const float m = smask[g];
    float x = sxyz[g*3+0], y = sxyz[g*3+1], z = sxyz[g*3+2];
    if (m <= 0.0f) { x = 1e30f; y = 1e30f; z = 1e30f; }
    pts4[g] = make_float4(x, y, z, 0.0f);
  }
  if (bt == 0) stats[t] = 0.0f;       // 256 floats: sum[128], sumsq[128]

  // read 64 channels x 64 j, coalesced along j
  const float* src = sfeat + (b*CIN)*N2D + j0;
#pragma unroll
  for (int i = 0; i < 16; ++i) {
    const int c = i*4 + (t >> 6);
    tile[c*65 + (t & 63)] = src[c*N2D + (t & 63)];
  }
  __syncthreads();
  // write featT[j][c], coalesced along c (float4)
  float* dstb = featT + (size_t)(b*N2D + j0) * CIN;
#pragma unroll
  for (int r = 0; r < 4; ++r) {
    const int j  = r*16 + (t >> 4);
    const int c4 = (t & 15) * 4;
    float4 v;
    v.x = tile[(c4+0)*65 + j];
    v.y = tile[(c4+1)*65 + j];
    v.z = tile[(c4+2)*65 + j];
    v.w = tile[(c4+3)*65 + j];
    *(float4*)(dstb + j*CIN + c4) = v;
  }
}

// ---------------------------------------------------------------------------
// main: ordered ball query + kernel-point weights + weighted feature sum.
// grid = 1024 blocks x 256 (8 queries per block, 2 per wave -> 4 blocks/CU)
// ---------------------------------------------------------------------------
__global__ __launch_bounds__(256) void pg_main(
    const float* __restrict__ qxyz, const float* __restrict__ sxyz,
    const float* __restrict__ qmask, const float4* __restrict__ pts4,
    const float* __restrict__ featT, const float* __restrict__ Kp,
    const float* __restrict__ KW, float* __restrict__ x1)
{
  __shared__ float4   s_pts[2][CHUNK];       // 8 KB, double-buffered staging
  __shared__ int      s_idx[QPB*NSAMP];      // 1 KB
  __shared__ int      s_cnt[QPB];
  __shared__ float    s_w[QPB*NSAMP*17];     // 17.4 KB (pad 17 breaks conflicts)
  __shared__ unsigned s_wm[QPB*NSAMP];       // 1 KB active-k bitmasks

  const int t    = threadIdx.x;
  const int lane = t & 63;
  const int wv   = t >> 6;
  const int gbase = blockIdx.x * QPB;        // 2048 % 8 == 0 -> single batch
  const int b     = gbase >> 11;

  // ---- phase 1: ordered ball query ----
  float qx[QPW], qy[QPW], qz[QPW];
  int cnt[QPW];
#pragma unroll
  for (int q = 0; q < QPW; ++q) {
    const int g = gbase + wv*QPW + q;
    qx[q] = qxyz[g*3+0]; qy[q] = qxyz[g*3+1]; qz[q] = qxyz[g*3+2];
    cnt[q] = 0;
  }

  const float4* bp = pts4 + b*N2D;
  float4 v = bp[t];                          // prefetch chunk 0
  bool wdone = false;
  const uint64_t lt = (1ull << lane) - 1ull;

  for (int ch = 0; ch < NCHUNK; ++ch) {
    const int buf = ch & 1;
    s_pts[buf][t] = v;
    if (ch + 1 < NCHUNK) v = bp[(ch+1)*CHUNK + t];   // prefetch next chunk
    __syncthreads();
    if (!wdone) {
#pragma unroll
      for (int sub = 0; sub < CHUNK/64; ++sub) {
        const float4 p = s_pts[buf][sub*64 + lane];
        const int jj = ch*CHUNK + sub*64 + lane;
#pragma unroll
        for (int q = 0; q < QPW; ++q) {
          const float dx = p.x - qx[q];
          const float dy = p.y - qy[q];
          const float dz = p.z - qz[q];
          const float d2 = dx*dx + dy*dy + dz*dz;
          const bool valid = d2 < RAD2;               // mask folded into coords
          const uint64_t m = __ballot(valid);
          if (valid) {
            const int pos = cnt[q] + __popcll(m & lt);
            if (pos < NSAMP) s_idx[(wv*QPW + q)*NSAMP + pos] = jj;
          }
          cnt[q] += (int)__popcll(m);
        }
      }
      if (cnt[0] >= NSAMP && cnt[1] >= NSAMP)
        wdone = true;                                  // wave-uniform skip
    }
  }

  if (lane == 0) {
#pragma unroll
    for (int q = 0; q < QPW; ++q) {
      int c = cnt[q]; if (c > NSAMP) c = NSAMP;
      s_cnt[wv*QPW + q] = c;
    }
  }
  __syncthreads();

  // ---- phase 2a: pad-normalize idx, rel vector, per-(q,s,k) weights ----
  // 256 threads == 256 (q,s) slots: thread t owns slot t (register-private)
  {
    const int qslot = t >> 5;
    const int s = t & 31;
    const int c = s_cnt[qslot];
    int j;
    if (s < c) {
      j = s_idx[t];
    } else {
      j = (c > 0) ? s_idx[qslot*NSAMP] : 0;   // pad with first neighbor
      s_idx[t] = j;
    }
    const int g = gbase + qslot;
    const float4 pj = pts4[b*N2D + j];
    const float rx = pj.x - qxyz[g*3+0];
    const float ry = pj.y - qxyz[g*3+1];
    const float rz = pj.z - qxyz[g*3+2];

    unsigned msk = 0u;
#pragma unroll
    for (int k = 0; k < NKP; ++k) {           // k uniform -> Kp scalar loads
      const float dx = rx - Kp[k*3+0];
      const float dy = ry - Kp[k*3+1];
      const float dz = rz - Kp[k*3+2];
      const float dd = dx*dx + dy*dy + dz*dz;
      const float w = 1.0f - sqrtf(dd) * INV_EXT;
      if (w > 0.0f) {
        s_w[t*17 + k] = w;
        msk |= (1u << k);
      }
    }
    s_wm[t] = msk;
  }
  __syncthreads();

  // ---- phase 2b: weighted feature aggregation (lane = channel) ----
  float kw[NKP];
#pragma unroll
  for (int k = 0; k < NKP; ++k) kw[k] = KW[k*CIN + lane];

#pragma unroll
  for (int qi = 0; qi < QPW; ++qi) {
    const int ql = wv*QPW + qi;
    const int g = gbase + ql;
    const float fpad = 1.0f - qmask[g];       // feature_mask = nb_mask + (1-qmask)
    const int c = __builtin_amdgcn_readfirstlane(s_cnt[ql]);

    // prefetch all 32 neighbor-feature gathers (independent, deep pipeline)
    float ft[NSAMP];
#pragma unroll
    for (int s = 0; s < NSAMP; ++s) {
      const int j = __builtin_amdgcn_readfirstlane(s_idx[ql*NSAMP + s]);
      ft[s] = featT[(size_t)(b*N2D + j)*CIN + lane];
    }

    float acc = 0.0f;
#pragma unroll
    for (int s = 0; s < NSAMP; ++s) {
      const float fm = ((s < c) ? 1.0f : 0.0f) + fpad;
      if (fm != 0.0f) {
        const unsigned mk =
            (unsigned)__builtin_amdgcn_readfirstlane((int)s_wm[ql*NSAMP + s]);
        if (mk != 0u) {
          const float* wp = &s_w[(ql*NSAMP + s)*17];
          float wsum = 0.0f;
#pragma unroll
          for (int k = 0; k < NKP; ++k)
            if (mk & (1u << k)) wsum += wp[k] * kw[k];   // kw[k] literal index
          acc = fmaf(fm*wsum, ft[s], acc);
        }
      }
    }
    x1[g*CIN + lane] = acc;
  }
}

// ---------------------------------------------------------------------------
// conv: out2[b,o,n] = sum_c W[o,c] * x1[g,c], fused BN sum/sumsq atomics.
// grid = 256 blocks x 256 (block = 64 queries x 64 output channels)
// ---------------------------------------------------------------------------
__global__ __launch_bounds__(256) void pg_conv(
    const float* __restrict__ x1, const float* __restrict__ Wout,
    float* __restrict__ out2, float* __restrict__ stats)
{
  __shared__ float s_x[64*65];
  const int t = threadIdx.x;
  const int lane = t & 63;
  const int wv = t >> 6;
  const int gt = blockIdx.x >> 1;
  const int oh = blockIdx.x & 1;
  const int g0 = gt * 64;
#pragma unroll
  for (int i = 0; i < 16; ++i) {
    const int idx = i*256 + t;
    s_x[(idx >> 6)*65 + (idx & 63)] = x1[g0*64 + idx];   // coalesced, +1 pad
  }
  __syncthreads();
  float xv[64];
#pragma unroll
  for (int cc = 0; cc < 64; ++cc) xv[cc] = s_x[lane*65 + cc];
  const int g = g0 + lane;
  const int bb = g >> 11;
  const int nn = g & 2047;
#pragma unroll
  for (int oi = 0; oi < 16; ++oi) {
    // force wave-uniform o -> W row becomes s_load from SGPRs
    const int o = __builtin_amdgcn_readfirstlane(oh*64 + wv*16 + oi);
    const float* wr = Wout + o*CIN;
    float acc = 0.0f;
#pragma unroll
    for (int cc = 0; cc < 64; ++cc) acc = fmaf(wr[cc], xv[cc], acc);
    out2[(bb*COUT + o)*N1D + nn] = acc;
    float s1 = acc, s2 = acc*acc;
#pragma unroll
    for (int off = 32; off; off >>= 1) {
      s1 += __shfl_xor(s1, off);
      s2 += __shfl_xor(s2, off);
    }
    if (lane == 0) {
      atomicAdd(&stats[o], s1);
      atomicAdd(&stats[COUT + o], s2);
    }
  }
}

// ---------------------------------------------------------------------------
// apply: BN (batch stats) + gamma/beta + ReLU.  grid = 1024 x 256, float4.
// ---------------------------------------------------------------------------
__global__ __launch_bounds__(256) void pg_apply(
    const float* __restrict__ out2, const float* __restrict__ stats,
    const float* __restrict__ gamma, const float* __restrict__ beta,
    float* __restrict__ dout)
{
  const int i = blockIdx.x*256 + threadIdx.x;   // float4 index
  const int flat = i*4;
  const int o = (flat >> 11) & 127;             // uniform per block
  const float inv = 1.0f / (float)(BATCH*N1D);
  const float mean = stats[o] * inv;
  const float var = stats[COUT + o] * inv - mean*mean;
  const float istd = rsqrtf(var + BN_EPS);
  const float ga = gamma[o] * istd;
  const float be = beta[o];
  const float4 x = ((const float4*)out2)[i];
  float4 y;
  y.x = fmaxf((x.x - mean)*ga + be, 0.0f);
  y.y = fmaxf((x.y - mean)*ga + be, 0.0f);
  y.z = fmaxf((x.z - mean)*ga + be, 0.0f);
  y.w = fmaxf((x.w - mean)*ga + be, 0.0f);
  ((float4*)dout)[i] = y;
}

extern "C" void kernel_launch(void* const* d_in, const int* in_sizes, int n_in,
                              void* d_out, int out_size, void* d_ws, size_t ws_size,
                              hipStream_t stream)
{
  const float* qxyz  = (const float*)d_in[0];
  const float* sxyz  = (const float*)d_in[1];
  const float* qmask = (const float*)d_in[2];
  const float* smask = (const float*)d_in[3];
  const float* sfeat = (const float*)d_in[4];
  const float* Kp    = (const float*)d_in[5];
  const float* KW    = (const float*)d_in[6];
  const float* Wout  = (const float*)d_in[7];
  const float* gamma = (const float*)d_in[8];
  const float* beta  = (const float*)d_in[9];
  float* ws = (float*)d_ws;
  float4* pts4 = (float4*)(ws + WS_PTS4);
  float* featT = ws + WS_FEATT;
  float* x1    = ws + WS_X1;
  float* out2  = ws + WS_OUT2;
  float* stats = ws + WS_STATS;
  float* dst   = (float*)d_out;

  pg_prep <<<512,  256, 0, stream>>>(sxyz, smask, sfeat, pts4, featT, stats);
  pg_main <<<1024, 256, 0, stream>>>(qxyz, sxyz, qmask, pts4, featT, Kp, KW, x1);
  pg_conv <<<256,  256, 0, stream>>>(x1, Wout, out2, stats);
  pg_apply<<<1024, 256, 0, stream>>>(out2, stats, gamma, beta, dst);
}

// Round 3
// 136.972 us; speedup vs baseline: 1.5022x; 1.2979x over previous
//
#include <hip/hip_runtime.h>
#include <stdint.h>

#define BATCH 4
#define N1D   2048
#define N2D   8192
#define NSAMP 32
#define NKP   15
#define CIN   64
#define COUT  128

#define RAD2    0.01f     // RADIUS^2
#define INV_EXT 25.0f     // 1 / EXTENT (EXTENT = 0.04)
#define BN_EPS  1e-5f

#define QPW   2                 // queries per wave
#define NWAVE 4                 // waves per block (block = 256)
#define QPB   (QPW*NWAVE)       // 8 queries per block
#define CHUNK 256               // staged support points per chunk
#define NCHUNK (N2D/CHUNK)      // 32

// ---- ws layout (in floats) ----
#define WS_PTS4   0                        // float4[B*N2]            131072 floats
#define WS_FEATT  131072                   // float [B*N2*CIN]       2097152 floats
#define WS_WT     (131072+2097152)         // float [CIN*COUT]  Wt[c][o] 8192 floats
#define WS_OUT2   (2228224+524288)         // float [B*COUT*N1]      1048576 floats
#define WS_STATS  (2752512+1048576)        // float [2*COUT] sums

// ---------------------------------------------------------------------------
// prep: LDS-tiled feature transpose (coalesced read AND write), point packing
// (mask folded into coords), W transpose.  grid = 513 x 256.
// ---------------------------------------------------------------------------
__global__ __launch_bounds__(256) void pg_prep(
    const float* __restrict__ sxyz, const float* __restrict__ smask,
    const float* __restrict__ sfeat, const float* __restrict__ Wout,
    float4* __restrict__ pts4, float* __restrict__ featT, float* __restrict__ Wt)
{
  __shared__ float tile[64*65];
  const int t  = threadIdx.x;
  const int bt = blockIdx.x;

  if (bt == 512) {        // build Wt[c][o] = W[o][c]  (coalesced writes)
#pragma unroll
    for (int i = 0; i < 32; ++i) {
      const int flat = i*256 + t;            // flat = c*128 + o
      Wt[flat] = Wout[(flat & 127)*CIN + (flat >> 7)];
    }
    return;
  }

  const int b  = bt >> 7;
  const int j0 = (bt & 127) * 64;

  // pack 64 support points per block (first wave)
  if (t < 64) {
    const int g = bt*64 + t;          // 512*64 = 32768 = B*N2
    const float m = smask[g];
    float x = sxyz[g*3+0], y = sxyz[g*3+1], z = sxyz[g*3+2];
    if (m <= 0.0f) { x = 1e30f; y = 1e30f; z = 1e30f; }
    pts4[g] = make_float4(x, y, z, 0.0f);
  }

  // read 64 channels x 64 j, coalesced along j
  const float* src = sfeat + (b*CIN)*N2D + j0;
#pragma unroll
  for (int i = 0; i < 16; ++i) {
    const int c = i*4 + (t >> 6);
    tile[c*65 + (t & 63)] = src[c*N2D + (t & 63)];
  }
  __syncthreads();
  // write featT[j][c], coalesced along c (float4)
  float* dstb = featT + (size_t)(b*N2D + j0) * CIN;
#pragma unroll
  for (int r = 0; r < 4; ++r) {
    const int j  = r*16 + (t >> 4);
    const int c4 = (t & 15) * 4;
    float4 v;
    v.x = tile[(c4+0)*65 + j];
    v.y = tile[(c4+1)*65 + j];
    v.z = tile[(c4+2)*65 + j];
    v.w = tile[(c4+3)*65 + j];
    *(float4*)(dstb + j*CIN + c4) = v;
  }
}

// ---------------------------------------------------------------------------
// main: ordered ball query + kernel-point weights + weighted feature sum
//       + fused 1x1 conv (writes out2 directly).
// grid = 1024 blocks x 256 (8 queries per block, 2 per wave)
// ---------------------------------------------------------------------------
__global__ __launch_bounds__(256) void pg_main(
    const float* __restrict__ qxyz, const float* __restrict__ sxyz,
    const float* __restrict__ qmask, const float4* __restrict__ pts4,
    const float* __restrict__ featT, const float* __restrict__ Kp,
    const float* __restrict__ KW, const float* __restrict__ Wt,
    float* __restrict__ out2)
{
  __shared__ float4   s_pts[2][CHUNK];       // 8 KB, double-buffered staging
  __shared__ int      s_idx[QPB*NSAMP];      // 1 KB
  __shared__ int      s_cnt[QPB];
  __shared__ float    s_w[QPB*NSAMP*17];     // 17.4 KB (pad 17 breaks conflicts)
  __shared__ unsigned s_wm[QPB*NSAMP];       // 1 KB active-k bitmasks
  __shared__ float    s_xq[QPB*65];          // 2 KB fused-conv x rows (pad 65)

  const int t    = threadIdx.x;
  const int lane = t & 63;
  const int wv   = t >> 6;
  const int gbase = blockIdx.x * QPB;        // 2048 % 8 == 0 -> single batch
  const int b     = gbase >> 11;

  // ---- phase 1: ordered ball query ----
  float qx[QPW], qy[QPW], qz[QPW];
  int cnt[QPW];
#pragma unroll
  for (int q = 0; q < QPW; ++q) {
    const int g = gbase + wv*QPW + q;
    qx[q] = qxyz[g*3+0]; qy[q] = qxyz[g*3+1]; qz[q] = qxyz[g*3+2];
    cnt[q] = 0;
  }

  const float4* bp = pts4 + b*N2D;
  float4 v = bp[t];                          // prefetch chunk 0
  bool wdone = false;
  const uint64_t lt = (1ull << lane) - 1ull;

  for (int ch = 0; ch < NCHUNK; ++ch) {
    const int buf = ch & 1;
    s_pts[buf][t] = v;
    if (ch + 1 < NCHUNK) v = bp[(ch+1)*CHUNK + t];   // prefetch next chunk
    __syncthreads();
    if (!wdone) {
#pragma unroll
      for (int sub = 0; sub < CHUNK/64; ++sub) {
        const float4 p = s_pts[buf][sub*64 + lane];
        const int jj = ch*CHUNK + sub*64 + lane;
#pragma unroll
        for (int q = 0; q < QPW; ++q) {
          const float dx = p.x - qx[q];
          const float dy = p.y - qy[q];
          const float dz = p.z - qz[q];
          const float d2 = dx*dx + dy*dy + dz*dz;
          const bool valid = d2 < RAD2;               // mask folded into coords
          const uint64_t m = __ballot(valid);
          if (valid) {
            const int pos = cnt[q] + __popcll(m & lt);
            if (pos < NSAMP) s_idx[(wv*QPW + q)*NSAMP + pos] = jj;
          }
          cnt[q] += (int)__popcll(m);
        }
      }
      if (cnt[0] >= NSAMP && cnt[1] >= NSAMP)
        wdone = true;                                  // wave-uniform skip
    }
  }

  if (lane == 0) {
#pragma unroll
    for (int q = 0; q < QPW; ++q) {
      int c = cnt[q]; if (c > NSAMP) c = NSAMP;
      s_cnt[wv*QPW + q] = c;
    }
  }
  __syncthreads();

  // ---- phase 2a: pad-normalize idx, rel vector, per-(q,s,k) weights ----
  // 256 threads == 256 (q,s) slots: thread t owns slot t (register-private)
  {
    const int qslot = t >> 5;
    const int s = t & 31;
    const int c = s_cnt[qslot];
    int j;
    if (s < c) {
      j = s_idx[t];
    } else {
      j = (c > 0) ? s_idx[qslot*NSAMP] : 0;   // pad with first neighbor
      s_idx[t] = j;
    }
    const int g = gbase + qslot;
    const float4 pj = pts4[b*N2D + j];
    const float rx = pj.x - qxyz[g*3+0];
    const float ry = pj.y - qxyz[g*3+1];
    const float rz = pj.z - qxyz[g*3+2];

    unsigned msk = 0u;
#pragma unroll
    for (int k = 0; k < NKP; ++k) {           // k uniform -> Kp scalar loads
      const float dx = rx - Kp[k*3+0];
      const float dy = ry - Kp[k*3+1];
      const float dz = rz - Kp[k*3+2];
      const float dd = dx*dx + dy*dy + dz*dz;
      const float w = 1.0f - sqrtf(dd) * INV_EXT;
      if (w > 0.0f) {
        s_w[t*17 + k] = w;
        msk |= (1u << k);
      }
    }
    s_wm[t] = msk;
  }
  __syncthreads();

  // ---- phase 2b: weighted feature aggregation (lane = channel) ----
  float kw[NKP];
#pragma unroll
  for (int k = 0; k < NKP; ++k) kw[k] = KW[k*CIN + lane];

#pragma unroll
  for (int qi = 0; qi < QPW; ++qi) {
    const int ql = wv*QPW + qi;
    const int g = gbase + ql;
    const float fpad = 1.0f - qmask[g];       // feature_mask = nb_mask + (1-qmask)
    const int c = __builtin_amdgcn_readfirstlane(s_cnt[ql]);

    // prefetch all 32 neighbor-feature gathers (independent, deep pipeline)
    float ft[NSAMP];
#pragma unroll
    for (int s = 0; s < NSAMP; ++s) {
      const int j = __builtin_amdgcn_readfirstlane(s_idx[ql*NSAMP + s]);
      ft[s] = featT[(size_t)(b*N2D + j)*CIN + lane];
    }

    float acc = 0.0f;
#pragma unroll
    for (int s = 0; s < NSAMP; ++s) {
      const float fm = ((s < c) ? 1.0f : 0.0f) + fpad;
      if (fm != 0.0f) {
        const unsigned mk =
            (unsigned)__builtin_amdgcn_readfirstlane((int)s_wm[ql*NSAMP + s]);
        if (mk != 0u) {
          const float* wp = &s_w[(ql*NSAMP + s)*17];
          float wsum = 0.0f;
#pragma unroll
          for (int k = 0; k < NKP; ++k)
            if (mk & (1u << k)) wsum += wp[k] * kw[k];   // kw[k] literal index
          acc = fmaf(fm*wsum, ft[s], acc);
        }
      }
    }
    s_xq[ql*65 + lane] = acc;                 // x row -> LDS for fused conv
  }
  __syncthreads();

  // ---- epilogue: fused 1x1 conv, 256 threads x 4 outputs ----
  // thread t: query slot n8 = t&7, o-group og = t>>3 (4 outputs og*4..og*4+3)
  {
    const int n8 = t & 7;
    const int og = t >> 3;
    const int g  = gbase + n8;
    const int nn = g & 2047;
    float a0 = 0.f, a1 = 0.f, a2 = 0.f, a3 = 0.f;
#pragma unroll
    for (int c = 0; c < CIN; ++c) {
      const float xc = s_xq[n8*65 + c];                       // 8-addr broadcast
      const float4 w4 = *(const float4*)(Wt + c*COUT + og*4); // 128B/wave, L1-hot
      a0 = fmaf(w4.x, xc, a0);
      a1 = fmaf(w4.y, xc, a1);
      a2 = fmaf(w4.z, xc, a2);
      a3 = fmaf(w4.w, xc, a3);
    }
    float* ob = out2 + (size_t)(b*COUT + og*4)*N1D + nn;
    ob[0]       = a0;
    ob[N1D]     = a1;
    ob[2*N1D]   = a2;
    ob[3*N1D]   = a3;
  }
}

// ---------------------------------------------------------------------------
// stats: per-o BN sum/sumsq over out2 (L2-resident), no atomics.
// grid = 128 blocks x 256 (one block per output channel)
// ---------------------------------------------------------------------------
__global__ __launch_bounds__(256) void pg_stats(
    const float* __restrict__ out2, float* __restrict__ stats)
{
  __shared__ float red[8];
  const int t = threadIdx.x;
  const int o = blockIdx.x;
  float s1 = 0.f, s2 = 0.f;
#pragma unroll
  for (int bb = 0; bb < BATCH; ++bb) {
    const float4* p = (const float4*)(out2 + (size_t)(bb*COUT + o)*N1D);
#pragma unroll
    for (int i = 0; i < 2; ++i) {
      const float4 x = p[i*256 + t];
      s1 += x.x + x.y + x.z + x.w;
      s2 += x.x*x.x + x.y*x.y + x.z*x.z + x.w*x.w;
    }
  }
#pragma unroll
  for (int off = 32; off; off >>= 1) {
    s1 += __shfl_xor(s1, off);
    s2 += __shfl_xor(s2, off);
  }
  const int wv = t >> 6;
  if ((t & 63) == 0) { red[wv] = s1; red[4+wv] = s2; }
  __syncthreads();
  if (t == 0) {
    stats[o]        = red[0]+red[1]+red[2]+red[3];
    stats[COUT + o] = red[4]+red[5]+red[6]+red[7];
  }
}

// ---------------------------------------------------------------------------
// apply: BN (batch stats) + gamma/beta + ReLU.  grid = 1024 x 256, float4.
// ---------------------------------------------------------------------------
__global__ __launch_bounds__(256) void pg_apply(
    const float* __restrict__ out2, const float* __restrict__ stats,
    const float* __restrict__ gamma, const float* __restrict__ beta,
    float* __restrict__ dout)
{
  const int i = blockIdx.x*256 + threadIdx.x;   // float4 index
  const int flat = i*4;
  const int o = (flat >> 11) & 127;             // uniform per block
  const float inv = 1.0f / (float)(BATCH*N1D);
  const float mean = stats[o] * inv;
  const float var = stats[COUT + o] * inv - mean*mean;
  const float istd = rsqrtf(var + BN_EPS);
  const float ga = gamma[o] * istd;
  const float be = beta[o];
  const float4 x = ((const float4*)out2)[i];
  float4 y;
  y.x = fmaxf((x.x - mean)*ga + be, 0.0f);
  y.y = fmaxf((x.y - mean)*ga + be, 0.0f);
  y.z = fmaxf((x.z - mean)*ga + be, 0.0f);
  y.w = fmaxf((x.w - mean)*ga + be, 0.0f);
  ((float4*)dout)[i] = y;
}

extern "C" void kernel_launch(void* const* d_in, const int* in_sizes, int n_in,
                              void* d_out, int out_size, void* d_ws, size_t ws_size,
                              hipStream_t stream)
{
  const float* qxyz  = (const float*)d_in[0];
  const float* sxyz  = (const float*)d_in[1];
  const float* qmask = (const float*)d_in[2];
  const float* smask = (const float*)d_in[3];
  const float* sfeat = (const float*)d_in[4];
  const float* Kp    = (const float*)d_in[5];
  const float* KW    = (const float*)d_in[6];
  const float* Wout  = (const float*)d_in[7];
  const float* gamma = (const float*)d_in[8];
  const float* beta  = (const float*)d_in[9];
  float* ws = (float*)d_ws;
  float4* pts4 = (float4*)(ws + WS_PTS4);
  float* featT = ws + WS_FEATT;
  float* Wt    = ws + WS_WT;
  float* out2  = ws + WS_OUT2;
  float* stats = ws + WS_STATS;
  float* dst   = (float*)d_out;

  pg_prep <<<513,  256, 0, stream>>>(sxyz, smask, sfeat, Wout, pts4, featT, Wt);
  pg_main <<<1024, 256, 0, stream>>>(qxyz, sxyz, qmask, pts4, featT, Kp, KW, Wt, out2);
  pg_stats<<<128,  256, 0, stream>>>(out2, stats);
  pg_apply<<<1024, 256, 0, stream>>>(out2, stats, gamma, beta, dst);
}